// Round 9
// baseline (364.104 us; speedup 1.0000x reference)
//
#include <hip/hip_runtime.h>
#include <hip/hip_bf16.h>
#include <stdint.h>

// MultiHeadSelfAttention: B=2,H=16,S=2048,D=1024,DK=64. fp32 interface, bf16 MFMA internals.
// d_out = out[2,2048,1024] fp32 ++ attn[2,16,2048,2048] fp32.
//
// R9: (a) attn VALU cut: native v_exp_f32 + v_cvt_pk_bf16_f32 P-pack.
//     (b) ABLATION: second attn launch (SINK=1) stores to an L2-resident dummy
//         (dead xb buffer) -> isolates non-store attn time. See decision table.

typedef __attribute__((ext_vector_type(4))) float f32x4;
typedef __attribute__((ext_vector_type(8))) short s16x8;
typedef __attribute__((ext_vector_type(4))) unsigned int u32x4;
typedef __attribute__((ext_vector_type(4))) unsigned short u16x4;

#define MFMA(a, b, c) __builtin_amdgcn_mfma_f32_16x16x32_bf16((a), (b), (c), 0, 0, 0)

#if __has_builtin(__builtin_amdgcn_exp2f)
#define EXP2(x) __builtin_amdgcn_exp2f(x)
#else
#define EXP2(x) exp2f(x)
#endif

__device__ __forceinline__ unsigned short f2bf(float f) {
    unsigned int u = __float_as_uint(f);
    unsigned int r = (u + 0x7FFFu + ((u >> 16) & 1u)) >> 16;
    return (unsigned short)r;
}
__device__ __forceinline__ unsigned int cvtpk_bf16(float lo, float hi) {
    unsigned int r;
    asm("v_cvt_pk_bf16_f32 %0, %1, %2" : "=v"(r) : "v"(lo), "v"(hi));
    return r;
}

// ---------------- Kernel 1: fp32 -> bf16 convert (x, wq, wk, wv, wo) ----------------
__global__ void convert_kernel(const float* __restrict__ x,
                               const float* __restrict__ wq, const float* __restrict__ wk,
                               const float* __restrict__ wv, const float* __restrict__ wo,
                               unsigned short* __restrict__ xb, unsigned short* __restrict__ wb) {
    size_t g = (size_t)blockIdx.x * blockDim.x + threadIdx.x;
    size_t i4 = g * 4;
    const float* src;
    unsigned short* dst;
    size_t off;
    if (i4 < 4194304) {            // x: 4096*1024
        src = x; dst = xb; off = i4;
    } else {
        size_t j = i4 - 4194304;
        int wsel = (int)(j >> 20); // each weight 1024*1024
        off = j & 1048575;
        src = (wsel == 0) ? wq : (wsel == 1) ? wk : (wsel == 2) ? wv : wo;
        dst = wb + ((size_t)wsel << 20);
    }
    float4 v = *(const float4*)(src + off);
    u16x4 o;
    o[0] = f2bf(v.x); o[1] = f2bf(v.y); o[2] = f2bf(v.z); o[3] = f2bf(v.w);
    *(u16x4*)(dst + off) = o;
}

// ---------------- Kernel 2/4: bt-GEMM, m97 structure ----------------
// mode 0 epilogue: Qs (scaled), Kb, and Vt with k-permuted columns (p = 8g+4ni+r per 32-block).
__global__ __launch_bounds__(256, 3) void gemm_kernel(
    const unsigned short* __restrict__ A, const unsigned short* __restrict__ B,
    const float* __restrict__ bias_q, const float* __restrict__ bias_k,
    const float* __restrict__ bias_v, int mode,
    unsigned short* __restrict__ Qs, unsigned short* __restrict__ Kb,
    unsigned short* __restrict__ Vt, float* __restrict__ outp) {
    const int t = threadIdx.x;
    const int lane = t & 63;
    const int wv4 = t >> 6;            // wave 0..3
    const int wr = wv4 >> 1, wc = wv4 & 1;
    const int rowbase = blockIdx.y * 128;
    const int colbase = blockIdx.x * 128;

    __shared__ __align__(16) unsigned short lA[128 * 64];
    __shared__ __align__(16) unsigned short lB[128 * 64];

    const int crow = lane >> 3;        // 0..7
    const int ccol = (lane & 7) * 8;   // 0..56

    f32x4 acc[4][4];
#pragma unroll
    for (int mi = 0; mi < 4; ++mi)
#pragma unroll
        for (int ni = 0; ni < 4; ++ni)
            acc[mi][ni] = (f32x4){0.f, 0.f, 0.f, 0.f};

    const int l15 = lane & 15;
    const int koff = (lane >> 4) * 8;
    const int ar = wr * 64 + l15;
    const int br = wc * 64 + l15;

    for (int kt = 0; kt < 16; ++kt) {
        const int kbase = kt * 64 + ccol;
#pragma unroll
        for (int i = 0; i < 4; ++i) {
            const int c = wv4 * 4 + i;
            const int r = c * 8 + crow;
            __builtin_amdgcn_global_load_lds(
                (const __attribute__((address_space(1))) void*)(A + (size_t)(rowbase + r) * 1024 + kbase),
                (__attribute__((address_space(3))) void*)&lA[c * 512], 16, 0, 0);
            __builtin_amdgcn_global_load_lds(
                (const __attribute__((address_space(1))) void*)(B + (size_t)(colbase + r) * 1024 + kbase),
                (__attribute__((address_space(3))) void*)&lB[c * 512], 16, 0, 0);
        }
        __syncthreads();
#pragma unroll
        for (int kk = 0; kk < 2; ++kk) {
            s16x8 af[4], bf[4];
#pragma unroll
            for (int mi = 0; mi < 4; ++mi)
                af[mi] = *(const s16x8*)&lA[(ar + mi * 16) * 64 + kk * 32 + koff];
#pragma unroll
            for (int ni = 0; ni < 4; ++ni)
                bf[ni] = *(const s16x8*)&lB[(br + ni * 16) * 64 + kk * 32 + koff];
#pragma unroll
            for (int mi = 0; mi < 4; ++mi)
#pragma unroll
                for (int ni = 0; ni < 4; ++ni)
                    acc[mi][ni] = MFMA(af[mi], bf[ni], acc[mi][ni]);
        }
        __syncthreads();
    }

    if (mode == 1) {
#pragma unroll
        for (int ni = 0; ni < 4; ++ni) {
            int n = colbase + wc * 64 + ni * 16 + l15;
            float bv = bias_q[n];
#pragma unroll
            for (int mi = 0; mi < 4; ++mi) {
#pragma unroll
                for (int reg = 0; reg < 4; ++reg) {
                    int m = rowbase + wr * 64 + mi * 16 + (lane >> 4) * 4 + reg;
                    outp[(size_t)m * 1024 + n] = acc[mi][ni][reg] + bv;
                }
            }
        }
    } else {
        const int proj = colbase >> 10;
        const float* bias = (proj == 0) ? bias_q : (proj == 1) ? bias_k : bias_v;
        const float scale = (proj == 0) ? 0.18033688011112042f : 1.0f;  // 0.125*log2(e)
#pragma unroll
        for (int ni = 0; ni < 4; ++ni) {
            int n = colbase + wc * 64 + ni * 16 + l15;
            int nn = n & 1023;
            int h = nn >> 6, d = nn & 63;
            float bv = bias[nn];
#pragma unroll
            for (int mi = 0; mi < 4; ++mi) {
                int m0 = rowbase + wr * 64 + mi * 16 + (lane >> 4) * 4;
                int b = m0 >> 11, s0 = m0 & 2047;
                if (proj == 2) {
                    u16x4 pk;
#pragma unroll
                    for (int reg = 0; reg < 4; ++reg)
                        pk[reg] = f2bf(acc[mi][ni][reg] + bv);
                    // k-permuted column within each 32-block: p = 8g + 4ni + r
                    int j0 = s0 & 31;
                    int pg = (j0 >> 2) & 3, pn = (j0 >> 4) & 1;
                    int pcol = (s0 & ~31) | (pg << 3) | (pn << 2);
                    *(u16x4*)&Vt[((size_t)(b * 16 + h) * 64 + d) * 2048 + pcol] = pk;
                } else {
                    unsigned short* dstp = (proj == 0) ? Qs : Kb;
#pragma unroll
                    for (int reg = 0; reg < 4; ++reg)
                        dstp[((size_t)(b * 16 + h) * 2048 + (s0 + reg)) * 64 + d] =
                            f2bf((acc[mi][ni][reg] + bv) * scale);
                }
            }
        }
    }
}

// ---------------- Kernel 3: attention (R7 barrier-free structure) ----------------
// SINK=0: real attn stores. SINK=1: stores to per-block 16KB window in `attn` param
// (dummy = dead xb buffer) -> L2-resident sink, isolates non-store time.
template <int SINK>
__global__ __launch_bounds__(256, 2) void attn_kernel(
    const unsigned short* __restrict__ Qs, const unsigned short* __restrict__ Kb,
    const unsigned short* __restrict__ Vt, float* __restrict__ attn,
    unsigned short* __restrict__ ctx) {
    const int t = threadIdx.x;
    const int lane = t & 63;
    const int l15 = lane & 15;
    const int g = lane >> 4;
    const int g4 = g * 4, g8 = g * 8;
    const int w = t >> 6;
    const int wr = w >> 1, wc = w & 1;
    const int qt = blockIdx.x;
    const int bh = blockIdx.y;
    const int b = bh >> 4, h = bh & 15;

    const unsigned short* Qh = Qs + (size_t)bh * (2048 * 64);
    const unsigned short* Kh = Kb + (size_t)bh * (2048 * 64);
    const unsigned short* Vh = Vt + (size_t)bh * (64 * 2048);
    float* attn_h = (SINK == 0)
                        ? attn + (size_t)bh * (2048 * 2048) + (size_t)(qt * 128) * 2048
                        : attn + (size_t)(bh * 16 + qt) * 4096;

    __shared__ float lred[2][128];
    __shared__ float lO[2][64 * 65];

    // Q fragments once (B-operand: rows = q)
    s16x8 qf[8];
#pragma unroll
    for (int mi = 0; mi < 4; ++mi)
#pragma unroll
        for (int kk = 0; kk < 2; ++kk)
            qf[mi * 2 + kk] =
                *(const s16x8*)&Qh[(size_t)(qt * 128 + wr * 64 + mi * 16 + l15) * 64 + kk * 32 + g8];

    s16x8 kf0[4], kf1[4], vf0[4], vf1[4];

#define K_LOAD(DST, KT)                                                                     \
    {                                                                                       \
        _Pragma("unroll") for (int ni = 0; ni < 2; ++ni)                                    \
            _Pragma("unroll") for (int kk = 0; kk < 2; ++kk)                                \
                DST[ni * 2 + kk] = *(const s16x8*)&Kh[(size_t)((KT) * 64 + wc * 32 +        \
                                                               ni * 16 + l15) * 64 +        \
                                                      kk * 32 + g8];                        \
    }
#define V_LOAD(DST, KT)                                                                     \
    {                                                                                       \
        _Pragma("unroll") for (int db = 0; db < 4; ++db)                                    \
            DST[db] = *(const s16x8*)&Vh[(size_t)(db * 16 + l15) * 2048 +                   \
                                         (KT) * 64 + wc * 32 + g8];                         \
    }
#define QK_MFMA(KF, SACC)                                                                   \
    {                                                                                       \
        _Pragma("unroll") for (int kk = 0; kk < 2; ++kk)                                    \
            _Pragma("unroll") for (int mi = 0; mi < 4; ++mi)                                \
                _Pragma("unroll") for (int ni = 0; ni < 2; ++ni)                            \
                    SACC[mi][ni] = MFMA(KF[ni * 2 + kk], qf[mi * 2 + kk], SACC[mi][ni]);    \
    }

    // ---- PASS 1: denominators (barrier-free) ----
    float qsum[4] = {0.f, 0.f, 0.f, 0.f};
    K_LOAD(kf0, 0);
#define P1_BODY(KF, KFN, KT)                                                                \
    {                                                                                       \
        f32x4 sacc[4][2];                                                                   \
        _Pragma("unroll") for (int mi = 0; mi < 4; ++mi)                                    \
            _Pragma("unroll") for (int ni = 0; ni < 2; ++ni)                                \
                sacc[mi][ni] = (f32x4){0.f, 0.f, 0.f, 0.f};                                 \
        QK_MFMA(KF, sacc);                                                                  \
        if ((KT) < 31) K_LOAD(KFN, (KT) + 1);                                               \
        _Pragma("unroll") for (int mi = 0; mi < 4; ++mi) {                                  \
            float e = 0.f;                                                                  \
            _Pragma("unroll") for (int ni = 0; ni < 2; ++ni)                                \
                _Pragma("unroll") for (int r = 0; r < 4; ++r)                               \
                    e += EXP2(sacc[mi][ni][r]);                                             \
            qsum[mi] += e;                                                                  \
        }                                                                                   \
    }
    for (int k2 = 0; k2 < 16; ++k2) {
        P1_BODY(kf0, kf1, 2 * k2);
        P1_BODY(kf1, kf0, 2 * k2 + 1);
    }
#pragma unroll
    for (int mi = 0; mi < 4; ++mi) {
        float v = qsum[mi];
        v += __shfl_xor(v, 16);
        v += __shfl_xor(v, 32);
        qsum[mi] = v;
    }
    if (lane < 16) {
#pragma unroll
        for (int mi = 0; mi < 4; ++mi)
            lred[wc][wr * 64 + mi * 16 + lane] = qsum[mi];
    }
    __syncthreads();
    float rl[4];
#pragma unroll
    for (int mi = 0; mi < 4; ++mi) {
        int q = wr * 64 + mi * 16 + l15;
        rl[mi] = 1.0f / (lred[0][q] + lred[1][q]);
    }

    // ---- PASS 2: barrier-free. attn float4 stores + cvt_pk P pack + PV partials ----
    f32x4 oacc[4][4];
#pragma unroll
    for (int mi = 0; mi < 4; ++mi)
#pragma unroll
        for (int db = 0; db < 4; ++db) oacc[mi][db] = (f32x4){0.f, 0.f, 0.f, 0.f};

    K_LOAD(kf0, 0);
    V_LOAD(vf0, 0);
#define P2_BODY(KF, KFN, VF, VFN, KT)                                                       \
    {                                                                                       \
        f32x4 sacc[4][2];                                                                   \
        _Pragma("unroll") for (int mi = 0; mi < 4; ++mi)                                    \
            _Pragma("unroll") for (int ni = 0; ni < 2; ++ni)                                \
                sacc[mi][ni] = (f32x4){0.f, 0.f, 0.f, 0.f};                                 \
        QK_MFMA(KF, sacc);                                                                  \
        if ((KT) < 31) {                                                                    \
            K_LOAD(KFN, (KT) + 1);                                                          \
            V_LOAD(VFN, (KT) + 1);                                                          \
        }                                                                                   \
        s16x8 pf[4];                                                                        \
        _Pragma("unroll") for (int mi = 0; mi < 4; ++mi) {                                  \
            const int q = wr * 64 + mi * 16 + l15;                                          \
            float p[8];                                                                     \
            _Pragma("unroll") for (int ni = 0; ni < 2; ++ni) {                              \
                p[ni * 4 + 0] = EXP2(sacc[mi][ni][0]) * rl[mi];                             \
                p[ni * 4 + 1] = EXP2(sacc[mi][ni][1]) * rl[mi];                             \
                p[ni * 4 + 2] = EXP2(sacc[mi][ni][2]) * rl[mi];                             \
                p[ni * 4 + 3] = EXP2(sacc[mi][ni][3]) * rl[mi];                             \
                float4 pv = {p[ni * 4 + 0], p[ni * 4 + 1], p[ni * 4 + 2], p[ni * 4 + 3]};   \
                size_t aidx = (size_t)q * 2048 + (KT) * 64 + wc * 32 + ni * 16 + g4;        \
                if (SINK) aidx &= 4095;                                                     \
                *(float4*)&attn_h[aidx] = pv;                                               \
            }                                                                               \
            u32x4 pkw;                                                                      \
            pkw[0] = cvtpk_bf16(p[0], p[1]);                                                \
            pkw[1] = cvtpk_bf16(p[2], p[3]);                                                \
            pkw[2] = cvtpk_bf16(p[4], p[5]);                                                \
            pkw[3] = cvtpk_bf16(p[6], p[7]);                                                \
            pf[mi] = *(const s16x8*)&pkw;                                                   \
        }                                                                                   \
        _Pragma("unroll") for (int mi = 0; mi < 4; ++mi)                                    \
            _Pragma("unroll") for (int db = 0; db < 4; ++db)                                \
                oacc[mi][db] = MFMA(pf[mi], VF[db], oacc[mi][db]);                          \
    }
    for (int k2 = 0; k2 < 16; ++k2) {
        P2_BODY(kf0, kf1, vf0, vf1, 2 * k2);
        P2_BODY(kf1, kf0, vf1, vf0, 2 * k2 + 1);
    }

    // ---- cross-wave O reduction (one barrier) + ctx write ----
    if (wc == 1) {
#pragma unroll
        for (int mi = 0; mi < 4; ++mi)
#pragma unroll
            for (int db = 0; db < 4; ++db)
#pragma unroll
                for (int r = 0; r < 4; ++r)
                    lO[wr][(mi * 16 + g4 + r) * 65 + db * 16 + l15] = oacc[mi][db][r];
    }
    __syncthreads();
    if (wc == 0) {
#pragma unroll
        for (int mi = 0; mi < 4; ++mi) {
#pragma unroll
            for (int db = 0; db < 4; ++db) {
#pragma unroll
                for (int r = 0; r < 4; ++r) {
                    float s = oacc[mi][db][r] + lO[wr][(mi * 16 + g4 + r) * 65 + db * 16 + l15];
                    int q = qt * 128 + wr * 64 + mi * 16 + g4 + r;
                    ctx[((size_t)(b * 2048 + q)) * 1024 + h * 64 + db * 16 + l15] = f2bf(s);
                }
            }
        }
    }
#undef K_LOAD
#undef V_LOAD
#undef QK_MFMA
#undef P1_BODY
#undef P2_BODY
}

// ---------------- launcher ----------------
extern "C" void kernel_launch(void* const* d_in, const int* in_sizes, int n_in,
                              void* d_out, int out_size, void* d_ws, size_t ws_size,
                              hipStream_t stream) {
    const float* x  = (const float*)d_in[0];
    const float* wq = (const float*)d_in[1];
    const float* bq = (const float*)d_in[2];
    const float* wk = (const float*)d_in[3];
    const float* bk = (const float*)d_in[4];
    const float* wv = (const float*)d_in[5];
    const float* bv = (const float*)d_in[6];
    const float* wo = (const float*)d_in[7];
    const float* bo = (const float*)d_in[8];

    char* ws = (char*)d_ws;
    unsigned short* xb  = (unsigned short*)(ws);                    // [4096][1024] bf16 (dead after gemm0 -> dummy sink)
    unsigned short* wb  = (unsigned short*)(ws + 8388608);          // [4][1024][1024] bf16
    unsigned short* Qsc = (unsigned short*)(ws + 16777216);         // [32][2048][64] bf16 (scaled)
    unsigned short* Kb  = (unsigned short*)(ws + 25165824);         // [32][2048][64] bf16
    unsigned short* Vt  = (unsigned short*)(ws + 33554432);         // [32][64][2048] bf16 (k-permuted)
    unsigned short* ctx = (unsigned short*)(ws + 41943040);         // [4096][1024] bf16

    float* out  = (float*)d_out;
    float* attn = out + 4194304;

    convert_kernel<<<8192, 256, 0, stream>>>(x, wq, wk, wv, wo, xb, wb);
    gemm_kernel<<<dim3(24, 32), 256, 0, stream>>>(xb, wb, bq, bk, bv, 0,
                                                  Qsc, Kb, Vt, nullptr);
    attn_kernel<0><<<dim3(16, 32), 256, 0, stream>>>(Qsc, Kb, Vt, attn, ctx);
    // ABLATION: identical kernel, stores sunk to L2-resident per-block window in xb.
    // xb is dead here and fully rewritten by convert_kernel on every replay.
    attn_kernel<1><<<dim3(16, 32), 256, 0, stream>>>(Qsc, Kb, Vt, (float*)xb, ctx);
    gemm_kernel<<<dim3(8, 32), 256, 0, stream>>>(ctx, wb + 3 * 1048576, bo, bo, bo, 1,
                                                 nullptr, nullptr, nullptr, out);
}

// Round 10
// 276.586 us; speedup vs baseline: 1.3164x; 1.3164x over previous
//
#include <hip/hip_runtime.h>
#include <hip/hip_bf16.h>
#include <stdint.h>

// MultiHeadSelfAttention: B=2,H=16,S=2048,D=1024,DK=64. fp32 interface, bf16 MFMA internals.
// d_out = out[2,2048,1024] fp32 ++ attn[2,16,2048,2048] fp32.
//
// R10: R7 barrier-free structure + VALU opts (native v_exp_f32, v_cvt_pk_bf16_f32),
// single attn launch. Clean A/B vs R7 (283 us): delta isolates the VALU opts.

typedef __attribute__((ext_vector_type(4))) float f32x4;
typedef __attribute__((ext_vector_type(8))) short s16x8;
typedef __attribute__((ext_vector_type(4))) unsigned int u32x4;
typedef __attribute__((ext_vector_type(4))) unsigned short u16x4;

#define MFMA(a, b, c) __builtin_amdgcn_mfma_f32_16x16x32_bf16((a), (b), (c), 0, 0, 0)

#if __has_builtin(__builtin_amdgcn_exp2f)
#define EXP2(x) __builtin_amdgcn_exp2f(x)
#else
#define EXP2(x) exp2f(x)
#endif

__device__ __forceinline__ unsigned short f2bf(float f) {
    unsigned int u = __float_as_uint(f);
    unsigned int r = (u + 0x7FFFu + ((u >> 16) & 1u)) >> 16;
    return (unsigned short)r;
}
__device__ __forceinline__ unsigned int cvtpk_bf16(float lo, float hi) {
    unsigned int r;
    asm("v_cvt_pk_bf16_f32 %0, %1, %2" : "=v"(r) : "v"(lo), "v"(hi));
    return r;
}

// ---------------- Kernel 1: fp32 -> bf16 convert (x, wq, wk, wv, wo) ----------------
__global__ void convert_kernel(const float* __restrict__ x,
                               const float* __restrict__ wq, const float* __restrict__ wk,
                               const float* __restrict__ wv, const float* __restrict__ wo,
                               unsigned short* __restrict__ xb, unsigned short* __restrict__ wb) {
    size_t g = (size_t)blockIdx.x * blockDim.x + threadIdx.x;
    size_t i4 = g * 4;
    const float* src;
    unsigned short* dst;
    size_t off;
    if (i4 < 4194304) {            // x: 4096*1024
        src = x; dst = xb; off = i4;
    } else {
        size_t j = i4 - 4194304;
        int wsel = (int)(j >> 20); // each weight 1024*1024
        off = j & 1048575;
        src = (wsel == 0) ? wq : (wsel == 1) ? wk : (wsel == 2) ? wv : wo;
        dst = wb + ((size_t)wsel << 20);
    }
    float4 v = *(const float4*)(src + off);
    u16x4 o;
    o[0] = f2bf(v.x); o[1] = f2bf(v.y); o[2] = f2bf(v.z); o[3] = f2bf(v.w);
    *(u16x4*)(dst + off) = o;
}

// ---------------- Kernel 2/4: bt-GEMM, m97 structure ----------------
// mode 0 epilogue: Qs (scaled), Kb, and Vt with k-permuted columns (p = 8g+4ni+r per 32-block).
__global__ __launch_bounds__(256, 3) void gemm_kernel(
    const unsigned short* __restrict__ A, const unsigned short* __restrict__ B,
    const float* __restrict__ bias_q, const float* __restrict__ bias_k,
    const float* __restrict__ bias_v, int mode,
    unsigned short* __restrict__ Qs, unsigned short* __restrict__ Kb,
    unsigned short* __restrict__ Vt, float* __restrict__ outp) {
    const int t = threadIdx.x;
    const int lane = t & 63;
    const int wv4 = t >> 6;            // wave 0..3
    const int wr = wv4 >> 1, wc = wv4 & 1;
    const int rowbase = blockIdx.y * 128;
    const int colbase = blockIdx.x * 128;

    __shared__ __align__(16) unsigned short lA[128 * 64];
    __shared__ __align__(16) unsigned short lB[128 * 64];

    const int crow = lane >> 3;        // 0..7
    const int ccol = (lane & 7) * 8;   // 0..56

    f32x4 acc[4][4];
#pragma unroll
    for (int mi = 0; mi < 4; ++mi)
#pragma unroll
        for (int ni = 0; ni < 4; ++ni)
            acc[mi][ni] = (f32x4){0.f, 0.f, 0.f, 0.f};

    const int l15 = lane & 15;
    const int koff = (lane >> 4) * 8;
    const int ar = wr * 64 + l15;
    const int br = wc * 64 + l15;

    for (int kt = 0; kt < 16; ++kt) {
        const int kbase = kt * 64 + ccol;
#pragma unroll
        for (int i = 0; i < 4; ++i) {
            const int c = wv4 * 4 + i;
            const int r = c * 8 + crow;
            __builtin_amdgcn_global_load_lds(
                (const __attribute__((address_space(1))) void*)(A + (size_t)(rowbase + r) * 1024 + kbase),
                (__attribute__((address_space(3))) void*)&lA[c * 512], 16, 0, 0);
            __builtin_amdgcn_global_load_lds(
                (const __attribute__((address_space(1))) void*)(B + (size_t)(colbase + r) * 1024 + kbase),
                (__attribute__((address_space(3))) void*)&lB[c * 512], 16, 0, 0);
        }
        __syncthreads();
#pragma unroll
        for (int kk = 0; kk < 2; ++kk) {
            s16x8 af[4], bf[4];
#pragma unroll
            for (int mi = 0; mi < 4; ++mi)
                af[mi] = *(const s16x8*)&lA[(ar + mi * 16) * 64 + kk * 32 + koff];
#pragma unroll
            for (int ni = 0; ni < 4; ++ni)
                bf[ni] = *(const s16x8*)&lB[(br + ni * 16) * 64 + kk * 32 + koff];
#pragma unroll
            for (int mi = 0; mi < 4; ++mi)
#pragma unroll
                for (int ni = 0; ni < 4; ++ni)
                    acc[mi][ni] = MFMA(af[mi], bf[ni], acc[mi][ni]);
        }
        __syncthreads();
    }

    if (mode == 1) {
#pragma unroll
        for (int ni = 0; ni < 4; ++ni) {
            int n = colbase + wc * 64 + ni * 16 + l15;
            float bv = bias_q[n];
#pragma unroll
            for (int mi = 0; mi < 4; ++mi) {
#pragma unroll
                for (int reg = 0; reg < 4; ++reg) {
                    int m = rowbase + wr * 64 + mi * 16 + (lane >> 4) * 4 + reg;
                    outp[(size_t)m * 1024 + n] = acc[mi][ni][reg] + bv;
                }
            }
        }
    } else {
        const int proj = colbase >> 10;
        const float* bias = (proj == 0) ? bias_q : (proj == 1) ? bias_k : bias_v;
        const float scale = (proj == 0) ? 0.18033688011112042f : 1.0f;  // 0.125*log2(e)
#pragma unroll
        for (int ni = 0; ni < 4; ++ni) {
            int n = colbase + wc * 64 + ni * 16 + l15;
            int nn = n & 1023;
            int h = nn >> 6, d = nn & 63;
            float bv = bias[nn];
#pragma unroll
            for (int mi = 0; mi < 4; ++mi) {
                int m0 = rowbase + wr * 64 + mi * 16 + (lane >> 4) * 4;
                int b = m0 >> 11, s0 = m0 & 2047;
                if (proj == 2) {
                    u16x4 pk;
#pragma unroll
                    for (int reg = 0; reg < 4; ++reg)
                        pk[reg] = f2bf(acc[mi][ni][reg] + bv);
                    // k-permuted column within each 32-block: p = 8g + 4ni + r
                    int j0 = s0 & 31;
                    int pg = (j0 >> 2) & 3, pn = (j0 >> 4) & 1;
                    int pcol = (s0 & ~31) | (pg << 3) | (pn << 2);
                    *(u16x4*)&Vt[((size_t)(b * 16 + h) * 64 + d) * 2048 + pcol] = pk;
                } else {
                    unsigned short* dstp = (proj == 0) ? Qs : Kb;
#pragma unroll
                    for (int reg = 0; reg < 4; ++reg)
                        dstp[((size_t)(b * 16 + h) * 2048 + (s0 + reg)) * 64 + d] =
                            f2bf((acc[mi][ni][reg] + bv) * scale);
                }
            }
        }
    }
}

// ---------------- Kernel 3: attention (R7 barrier-free structure + VALU opts) ----------------
__global__ __launch_bounds__(256, 2) void attn_kernel(
    const unsigned short* __restrict__ Qs, const unsigned short* __restrict__ Kb,
    const unsigned short* __restrict__ Vt, float* __restrict__ attn,
    unsigned short* __restrict__ ctx) {
    const int t = threadIdx.x;
    const int lane = t & 63;
    const int l15 = lane & 15;
    const int g = lane >> 4;
    const int g4 = g * 4, g8 = g * 8;
    const int w = t >> 6;
    const int wr = w >> 1, wc = w & 1;
    const int qt = blockIdx.x;
    const int bh = blockIdx.y;
    const int b = bh >> 4, h = bh & 15;

    const unsigned short* Qh = Qs + (size_t)bh * (2048 * 64);
    const unsigned short* Kh = Kb + (size_t)bh * (2048 * 64);
    const unsigned short* Vh = Vt + (size_t)bh * (64 * 2048);
    float* attn_h = attn + (size_t)bh * (2048 * 2048) + (size_t)(qt * 128) * 2048;

    __shared__ float lred[2][128];
    __shared__ float lO[2][64 * 65];

    // Q fragments once (B-operand: rows = q)
    s16x8 qf[8];
#pragma unroll
    for (int mi = 0; mi < 4; ++mi)
#pragma unroll
        for (int kk = 0; kk < 2; ++kk)
            qf[mi * 2 + kk] =
                *(const s16x8*)&Qh[(size_t)(qt * 128 + wr * 64 + mi * 16 + l15) * 64 + kk * 32 + g8];

    s16x8 kf0[4], kf1[4], vf0[4], vf1[4];

#define K_LOAD(DST, KT)                                                                     \
    {                                                                                       \
        _Pragma("unroll") for (int ni = 0; ni < 2; ++ni)                                    \
            _Pragma("unroll") for (int kk = 0; kk < 2; ++kk)                                \
                DST[ni * 2 + kk] = *(const s16x8*)&Kh[(size_t)((KT) * 64 + wc * 32 +        \
                                                               ni * 16 + l15) * 64 +        \
                                                      kk * 32 + g8];                        \
    }
#define V_LOAD(DST, KT)                                                                     \
    {                                                                                       \
        _Pragma("unroll") for (int db = 0; db < 4; ++db)                                    \
            DST[db] = *(const s16x8*)&Vh[(size_t)(db * 16 + l15) * 2048 +                   \
                                         (KT) * 64 + wc * 32 + g8];                         \
    }
#define QK_MFMA(KF, SACC)                                                                   \
    {                                                                                       \
        _Pragma("unroll") for (int kk = 0; kk < 2; ++kk)                                    \
            _Pragma("unroll") for (int mi = 0; mi < 4; ++mi)                                \
                _Pragma("unroll") for (int ni = 0; ni < 2; ++ni)                            \
                    SACC[mi][ni] = MFMA(KF[ni * 2 + kk], qf[mi * 2 + kk], SACC[mi][ni]);    \
    }

    // ---- PASS 1: denominators (barrier-free) ----
    float qsum[4] = {0.f, 0.f, 0.f, 0.f};
    K_LOAD(kf0, 0);
#define P1_BODY(KF, KFN, KT)                                                                \
    {                                                                                       \
        f32x4 sacc[4][2];                                                                   \
        _Pragma("unroll") for (int mi = 0; mi < 4; ++mi)                                    \
            _Pragma("unroll") for (int ni = 0; ni < 2; ++ni)                                \
                sacc[mi][ni] = (f32x4){0.f, 0.f, 0.f, 0.f};                                 \
        QK_MFMA(KF, sacc);                                                                  \
        if ((KT) < 31) K_LOAD(KFN, (KT) + 1);                                               \
        _Pragma("unroll") for (int mi = 0; mi < 4; ++mi) {                                  \
            float e = 0.f;                                                                  \
            _Pragma("unroll") for (int ni = 0; ni < 2; ++ni)                                \
                _Pragma("unroll") for (int r = 0; r < 4; ++r)                               \
                    e += EXP2(sacc[mi][ni][r]);                                             \
            qsum[mi] += e;                                                                  \
        }                                                                                   \
    }
    for (int k2 = 0; k2 < 16; ++k2) {
        P1_BODY(kf0, kf1, 2 * k2);
        P1_BODY(kf1, kf0, 2 * k2 + 1);
    }
#pragma unroll
    for (int mi = 0; mi < 4; ++mi) {
        float v = qsum[mi];
        v += __shfl_xor(v, 16);
        v += __shfl_xor(v, 32);
        qsum[mi] = v;
    }
    if (lane < 16) {
#pragma unroll
        for (int mi = 0; mi < 4; ++mi)
            lred[wc][wr * 64 + mi * 16 + lane] = qsum[mi];
    }
    __syncthreads();
    float rl[4];
#pragma unroll
    for (int mi = 0; mi < 4; ++mi) {
        int q = wr * 64 + mi * 16 + l15;
        rl[mi] = 1.0f / (lred[0][q] + lred[1][q]);
    }

    // ---- PASS 2: barrier-free. attn float4 stores + cvt_pk P pack + PV partials ----
    f32x4 oacc[4][4];
#pragma unroll
    for (int mi = 0; mi < 4; ++mi)
#pragma unroll
        for (int db = 0; db < 4; ++db) oacc[mi][db] = (f32x4){0.f, 0.f, 0.f, 0.f};

    K_LOAD(kf0, 0);
    V_LOAD(vf0, 0);
#define P2_BODY(KF, KFN, VF, VFN, KT)                                                       \
    {                                                                                       \
        f32x4 sacc[4][2];                                                                   \
        _Pragma("unroll") for (int mi = 0; mi < 4; ++mi)                                    \
            _Pragma("unroll") for (int ni = 0; ni < 2; ++ni)                                \
                sacc[mi][ni] = (f32x4){0.f, 0.f, 0.f, 0.f};                                 \
        QK_MFMA(KF, sacc);                                                                  \
        if ((KT) < 31) {                                                                    \
            K_LOAD(KFN, (KT) + 1);                                                          \
            V_LOAD(VFN, (KT) + 1);                                                          \
        }                                                                                   \
        s16x8 pf[4];                                                                        \
        _Pragma("unroll") for (int mi = 0; mi < 4; ++mi) {                                  \
            const int q = wr * 64 + mi * 16 + l15;                                          \
            float p[8];                                                                     \
            _Pragma("unroll") for (int ni = 0; ni < 2; ++ni) {                              \
                p[ni * 4 + 0] = EXP2(sacc[mi][ni][0]) * rl[mi];                             \
                p[ni * 4 + 1] = EXP2(sacc[mi][ni][1]) * rl[mi];                             \
                p[ni * 4 + 2] = EXP2(sacc[mi][ni][2]) * rl[mi];                             \
                p[ni * 4 + 3] = EXP2(sacc[mi][ni][3]) * rl[mi];                             \
                float4 pv = {p[ni * 4 + 0], p[ni * 4 + 1], p[ni * 4 + 2], p[ni * 4 + 3]};   \
                *(float4*)&attn_h[(size_t)q * 2048 + (KT) * 64 + wc * 32 + ni * 16 + g4] =  \
                    pv;                                                                     \
            }                                                                               \
            u32x4 pkw;                                                                      \
            pkw[0] = cvtpk_bf16(p[0], p[1]);                                                \
            pkw[1] = cvtpk_bf16(p[2], p[3]);                                                \
            pkw[2] = cvtpk_bf16(p[4], p[5]);                                                \
            pkw[3] = cvtpk_bf16(p[6], p[7]);                                                \
            pf[mi] = *(const s16x8*)&pkw;                                                   \
        }                                                                                   \
        _Pragma("unroll") for (int mi = 0; mi < 4; ++mi)                                    \
            _Pragma("unroll") for (int db = 0; db < 4; ++db)                                \
                oacc[mi][db] = MFMA(pf[mi], VF[db], oacc[mi][db]);                          \
    }
    for (int k2 = 0; k2 < 16; ++k2) {
        P2_BODY(kf0, kf1, vf0, vf1, 2 * k2);
        P2_BODY(kf1, kf0, vf1, vf0, 2 * k2 + 1);
    }

    // ---- cross-wave O reduction (one barrier) + ctx write ----
    if (wc == 1) {
#pragma unroll
        for (int mi = 0; mi < 4; ++mi)
#pragma unroll
            for (int db = 0; db < 4; ++db)
#pragma unroll
                for (int r = 0; r < 4; ++r)
                    lO[wr][(mi * 16 + g4 + r) * 65 + db * 16 + l15] = oacc[mi][db][r];
    }
    __syncthreads();
    if (wc == 0) {
#pragma unroll
        for (int mi = 0; mi < 4; ++mi) {
#pragma unroll
            for (int db = 0; db < 4; ++db) {
#pragma unroll
                for (int r = 0; r < 4; ++r) {
                    float s = oacc[mi][db][r] + lO[wr][(mi * 16 + g4 + r) * 65 + db * 16 + l15];
                    int q = qt * 128 + wr * 64 + mi * 16 + g4 + r;
                    ctx[((size_t)(b * 2048 + q)) * 1024 + h * 64 + db * 16 + l15] = f2bf(s);
                }
            }
        }
    }
#undef K_LOAD
#undef V_LOAD
#undef QK_MFMA
#undef P1_BODY
#undef P2_BODY
}

// ---------------- launcher ----------------
extern "C" void kernel_launch(void* const* d_in, const int* in_sizes, int n_in,
                              void* d_out, int out_size, void* d_ws, size_t ws_size,
                              hipStream_t stream) {
    const float* x  = (const float*)d_in[0];
    const float* wq = (const float*)d_in[1];
    const float* bq = (const float*)d_in[2];
    const float* wk = (const float*)d_in[3];
    const float* bk = (const float*)d_in[4];
    const float* wv = (const float*)d_in[5];
    const float* bv = (const float*)d_in[6];
    const float* wo = (const float*)d_in[7];
    const float* bo = (const float*)d_in[8];

    char* ws = (char*)d_ws;
    unsigned short* xb  = (unsigned short*)(ws);                    // [4096][1024] bf16
    unsigned short* wb  = (unsigned short*)(ws + 8388608);          // [4][1024][1024] bf16
    unsigned short* Qsc = (unsigned short*)(ws + 16777216);         // [32][2048][64] bf16 (scaled)
    unsigned short* Kb  = (unsigned short*)(ws + 25165824);         // [32][2048][64] bf16
    unsigned short* Vt  = (unsigned short*)(ws + 33554432);         // [32][64][2048] bf16 (k-permuted)
    unsigned short* ctx = (unsigned short*)(ws + 41943040);         // [4096][1024] bf16

    float* out  = (float*)d_out;
    float* attn = out + 4194304;

    convert_kernel<<<8192, 256, 0, stream>>>(x, wq, wk, wv, wo, xb, wb);
    gemm_kernel<<<dim3(24, 32), 256, 0, stream>>>(xb, wb, bq, bk, bv, 0,
                                                  Qsc, Kb, Vt, nullptr);
    attn_kernel<<<dim3(16, 32), 256, 0, stream>>>(Qsc, Kb, Vt, attn, ctx);
    gemm_kernel<<<dim3(8, 32), 256, 0, stream>>>(ctx, wb + 3 * 1048576, bo, bo, bo, 1,
                                                 nullptr, nullptr, nullptr, out);
}